// Round 1
// baseline (62.971 us; speedup 1.0000x reference)
//
#include <hip/hip_runtime.h>

// YOLO loss, fully fused single pass.
// pred/target: [B=16384, S=7, S=7, C=30] fp32, cell-contiguous (30 floats).
// 802816 cells = 3136 blocks * 256 cells. Memory-bound streaming reduction.

#define LAMBDA_COORD 5.0f
#define LAMBDA_NOOBJ 0.5f

constexpr int C_FIELDS = 30;
constexpr int CELLS_PER_BLOCK = 256;
constexpr int TILE_FLOATS = CELLS_PER_BLOCK * C_FIELDS;  // 7680
constexpr int TILE_VEC4 = TILE_FLOATS / 4;               // 1920

__global__ __launch_bounds__(256) void yolo_loss_kernel(
    const float* __restrict__ pred, const float* __restrict__ targ,
    float* __restrict__ out, float inv_b)
{
    __shared__ float sp[TILE_FLOATS];   // 30720 B
    __shared__ float st[TILE_FLOATS];   // 30720 B
    __shared__ float red[4];

    const int tid = threadIdx.x;
    const long long base = (long long)blockIdx.x * TILE_FLOATS;

    // Coalesced staging: 16 B/lane float4 loads. Block base is 30720 B -> 16B aligned.
    const float4* pv = (const float4*)(pred + base);
    const float4* tv = (const float4*)(targ + base);
    float4* spv = (float4*)sp;
    float4* stv = (float4*)st;
    #pragma unroll
    for (int k = 0; k < 8; ++k) {
        int i = tid + k * 256;
        if (i < TILE_VEC4) {            // 1920 = 7.5 * 256
            spv[i] = pv[i];
            stv[i] = tv[i];
        }
    }
    __syncthreads();

    // Each thread owns one cell.
    const float* p = sp + tid * C_FIELDS;
    const float* t = st + tid * C_FIELDS;

    const float tx0 = t[0], ty0 = t[1], tx1 = t[2], ty1 = t[3], t4 = t[4];
    const float a2 = (tx1 - tx0) * (ty1 - ty0);

    // Box A = pred[0:4], Box B = pred[5:9]
    const float ax0 = p[0], ay0 = p[1], ax1 = p[2], ay1 = p[3];
    const float bx0 = p[5], by0 = p[6], bx1 = p[7], by1 = p[8];

    const float wA = fmaxf(fminf(ax1, tx1) - fmaxf(ax0, tx0), 0.0f);
    const float hA = fmaxf(fminf(ay1, ty1) - fmaxf(ay0, ty0), 0.0f);
    const float interA = wA * hA;
    const float a1A = (ax1 - ax0) * (ay1 - ay0);
    const float iouA = interA / (a1A + a2 - interA);

    const float wB = fmaxf(fminf(bx1, tx1) - fmaxf(bx0, tx0), 0.0f);
    const float hB = fmaxf(fminf(by1, ty1) - fmaxf(by0, ty0), 0.0f);
    const float interB = wB * hB;
    const float a1B = (bx1 - bx0) * (by1 - by0);
    const float iouB = interB / (a1B + a2 - interB);

    // np.argmax semantics over 2 elems: NaN treated as max, first index wins ties.
    bool pickB;
    if (iouA != iouA)      pickB = false;   // iouA is NaN -> index 0
    else if (iouB != iouB) pickB = true;    // iouB is NaN -> index 1
    else                   pickB = (iouB > iouA);

    const float c0 = pickB ? bx0 : ax0;
    const float c1 = pickB ? by0 : ay0;
    const float c2 = pickB ? bx1 : ax1;
    const float c3 = pickB ? by1 : ay1;

    const bool obj = (t4 > 0.0f);

    // loss1: (where(obj, chosen_xy, 0) - t_xy)^2
    const float dx = (obj ? c0 : 0.0f) - tx0;
    const float dy = (obj ? c1 : 0.0f) - ty0;
    const float l1 = dx * dx + dy * dy;

    // loss2: objf*(sqrt(where(obj,chosen_wh,1)) - sqrt(t_wh))^2 + (1-objf)*sqrt(t_wh)^2
    const float stw = sqrtf(tx1);
    const float sth = sqrtf(ty1);
    float l2;
    if (obj) {
        const float d0 = sqrtf(c2) - stw;
        const float d1 = sqrtf(c3) - sth;
        l2 = d0 * d0 + d1 * d1;
    } else {
        l2 = stw * stw + sth * sth;
    }

    const float conf = p[4];
    const float v3 = (obj ? conf : 0.0f) - t4;
    const float l3 = v3 * v3;
    const float v4 = (obj ? 1.0f : conf) - t4;
    const float l4 = v4 * v4;

    float l5 = 0.0f;
    #pragma unroll
    for (int f = 10; f < 30; ++f) {
        const float v = (obj ? p[f] : 0.0f) - t[f];
        l5 += v * v;
    }

    float cell = LAMBDA_COORD * (l1 + l2) + l3 + LAMBDA_NOOBJ * l4 + l5;

    // Wave-64 butterfly reduce.
    #pragma unroll
    for (int off = 32; off >= 1; off >>= 1)
        cell += __shfl_xor(cell, off, 64);

    const int wave = tid >> 6;
    const int lane = tid & 63;
    if (lane == 0) red[wave] = cell;
    __syncthreads();
    if (tid == 0) {
        const float s = red[0] + red[1] + red[2] + red[3];
        atomicAdd(out, s * inv_b);
    }
}

extern "C" void kernel_launch(void* const* d_in, const int* in_sizes, int n_in,
                              void* d_out, int out_size, void* d_ws, size_t ws_size,
                              hipStream_t stream) {
    const float* pred = (const float*)d_in[0];
    const float* targ = (const float*)d_in[1];
    float* out = (float*)d_out;

    const long long total = (long long)in_sizes[0];          // B*S*S*30
    const long long cells = total / C_FIELDS;                // 802816
    const long long B = cells / 49;                          // 16384
    const int blocks = (int)(cells / CELLS_PER_BLOCK);       // 3136 (exact)
    const float inv_b = 1.0f / (float)B;

    hipMemsetAsync(d_out, 0, sizeof(float), stream);
    yolo_loss_kernel<<<blocks, 256, 0, stream>>>(pred, targ, out, inv_b);
}

// Round 2
// 60.392 us; speedup vs baseline: 1.0427x; 1.0427x over previous
//
#include <hip/hip_runtime.h>

// YOLO loss, fused single pass, memory-bound streaming reduction.
// pred/target: [B=16384, 7, 7, 30] fp32, cell = 30 contiguous floats (120 B).
// 802816 cells = 3136 blocks x 256 cells.
//
// R1 change: single 30 KB LDS buffer time-shared between target and pred
// (stage targ -> extract 25 floats to regs -> restage pred -> compute).
// LDS/block 62KB -> 30.7KB => 5 blocks/CU (20 waves/CU vs 8 before).
// Staging via global_load_lds width=16 (wave-uniform LDS base + lane*16,
// layout is linear so this is exact).

#define LAMBDA_COORD 5.0f
#define LAMBDA_NOOBJ 0.5f

constexpr int C_FIELDS = 30;
constexpr int CELLS_PER_BLOCK = 256;
constexpr int TILE_FLOATS = CELLS_PER_BLOCK * C_FIELDS;  // 7680 floats = 30720 B
constexpr int CHUNKS = (TILE_FLOATS * 4) / 1024;         // 30 chunks of 1024 B (64 lanes x 16 B)

__global__ __launch_bounds__(256, 5) void yolo_loss_kernel(
    const float* __restrict__ pred, const float* __restrict__ targ,
    float* __restrict__ out, float inv_b)
{
    __shared__ float sbuf[TILE_FLOATS];   // 30720 B, time-shared targ then pred
    __shared__ float red[4];

    const int tid = threadIdx.x;
    const int wave = tid >> 6;
    const int lane = tid & 63;
    const long long base = (long long)blockIdx.x * TILE_FLOATS;

    // ---- Phase 1: stage TARGET tile, coalesced direct-to-LDS ----
    #pragma unroll
    for (int c = wave; c < CHUNKS; c += 4) {
        const float* g = targ + base + c * 256 + lane * 4;   // per-lane global src
        __builtin_amdgcn_global_load_lds(
            (const __attribute__((address_space(1))) unsigned int*)g,
            (__attribute__((address_space(3))) unsigned int*)&sbuf[c * 256],  // wave-uniform dst
            16, 0, 0);
    }
    __syncthreads();   // compiler drains vmcnt before barrier -> data ready

    // Extract my cell's target fields into registers (held across restage).
    const float* t = sbuf + tid * C_FIELDS;
    const float tx0 = t[0], ty0 = t[1], tx1 = t[2], ty1 = t[3], t4 = t[4];
    float tc[20];
    #pragma unroll
    for (int f = 0; f < 20; ++f) tc[f] = t[10 + f];
    __syncthreads();   // all reads done before overwrite

    // ---- Phase 2: stage PRED tile into the same buffer ----
    #pragma unroll
    for (int c = wave; c < CHUNKS; c += 4) {
        const float* g = pred + base + c * 256 + lane * 4;
        __builtin_amdgcn_global_load_lds(
            (const __attribute__((address_space(1))) unsigned int*)g,
            (__attribute__((address_space(3))) unsigned int*)&sbuf[c * 256],
            16, 0, 0);
    }
    __syncthreads();

    const float* p = sbuf + tid * C_FIELDS;

    const float a2 = (tx1 - tx0) * (ty1 - ty0);

    // Box A = pred[0:4], Box B = pred[5:9]
    const float ax0 = p[0], ay0 = p[1], ax1 = p[2], ay1 = p[3];
    const float conf = p[4];
    const float bx0 = p[5], by0 = p[6], bx1 = p[7], by1 = p[8];

    const float wA = fmaxf(fminf(ax1, tx1) - fmaxf(ax0, tx0), 0.0f);
    const float hA = fmaxf(fminf(ay1, ty1) - fmaxf(ay0, ty0), 0.0f);
    const float interA = wA * hA;
    const float a1A = (ax1 - ax0) * (ay1 - ay0);
    const float iouA = interA / (a1A + a2 - interA);

    const float wB = fmaxf(fminf(bx1, tx1) - fmaxf(bx0, tx0), 0.0f);
    const float hB = fmaxf(fminf(by1, ty1) - fmaxf(by0, ty0), 0.0f);
    const float interB = wB * hB;
    const float a1B = (bx1 - bx0) * (by1 - by0);
    const float iouB = interB / (a1B + a2 - interB);

    // np.argmax over 2: NaN acts as max, first index wins ties.
    bool pickB;
    if (iouA != iouA)      pickB = false;
    else if (iouB != iouB) pickB = true;
    else                   pickB = (iouB > iouA);

    const float c0 = pickB ? bx0 : ax0;
    const float c1 = pickB ? by0 : ay0;
    const float c2 = pickB ? bx1 : ax1;
    const float c3 = pickB ? by1 : ay1;

    const bool obj = (t4 > 0.0f);

    // loss1
    const float dx = (obj ? c0 : 0.0f) - tx0;
    const float dy = (obj ? c1 : 0.0f) - ty0;
    const float l1 = dx * dx + dy * dy;

    // loss2
    const float stw = sqrtf(tx1);
    const float sth = sqrtf(ty1);
    float l2;
    if (obj) {
        const float d0 = sqrtf(c2) - stw;
        const float d1 = sqrtf(c3) - sth;
        l2 = d0 * d0 + d1 * d1;
    } else {
        l2 = stw * stw + sth * sth;
    }

    // loss3 / loss4
    const float v3 = (obj ? conf : 0.0f) - t4;
    const float l3 = v3 * v3;
    const float v4 = (obj ? 1.0f : conf) - t4;
    const float l4 = v4 * v4;

    // loss5 (cls)
    float l5 = 0.0f;
    #pragma unroll
    for (int f = 0; f < 20; ++f) {
        const float v = (obj ? p[10 + f] : 0.0f) - tc[f];
        l5 += v * v;
    }

    float cell = LAMBDA_COORD * (l1 + l2) + l3 + LAMBDA_NOOBJ * l4 + l5;

    // Wave-64 butterfly reduce.
    #pragma unroll
    for (int off = 32; off >= 1; off >>= 1)
        cell += __shfl_xor(cell, off, 64);

    if (lane == 0) red[wave] = cell;
    __syncthreads();
    if (tid == 0) {
        const float s = red[0] + red[1] + red[2] + red[3];
        atomicAdd(out, s * inv_b);
    }
}

extern "C" void kernel_launch(void* const* d_in, const int* in_sizes, int n_in,
                              void* d_out, int out_size, void* d_ws, size_t ws_size,
                              hipStream_t stream) {
    const float* pred = (const float*)d_in[0];
    const float* targ = (const float*)d_in[1];
    float* out = (float*)d_out;

    const long long total = (long long)in_sizes[0];     // B*49*30
    const long long cells = total / C_FIELDS;           // 802816
    const long long B = cells / 49;                     // 16384
    const int blocks = (int)(cells / CELLS_PER_BLOCK);  // 3136 exact
    const float inv_b = 1.0f / (float)B;

    hipMemsetAsync(d_out, 0, sizeof(float), stream);
    yolo_loss_kernel<<<blocks, 256, 0, stream>>>(pred, targ, out, inv_b);
}

// Round 3
// 59.704 us; speedup vs baseline: 1.0547x; 1.0115x over previous
//
#include <hip/hip_runtime.h>

// YOLO loss, fused single pass. R2: no LDS, no barriers — each thread loads
// its own 120 B cell from pred and target directly into registers via
// 7x16B + 1x8B wide loads (cell base i*120 is 8B-aligned; memcpy lowers to
// global_load_dwordx4/x2). A wave's 16 loads cover one contiguous 15 KB
// region -> every fetched byte is used; L1 merges intra-wave overlap.
// All 16 loads issue before first use: latency hidden by ILP x TLP.

#define LAMBDA_COORD 5.0f
#define LAMBDA_NOOBJ 0.5f

constexpr int C_FIELDS = 30;

__global__ __launch_bounds__(256) void yolo_loss_kernel(
    const float* __restrict__ pred, const float* __restrict__ targ,
    float* __restrict__ out, float inv_b)
{
    __shared__ float red[4];

    const int tid = threadIdx.x;
    const long long cell = (long long)blockIdx.x * 256 + tid;
    const float* __restrict__ pb = pred + cell * C_FIELDS;
    const float* __restrict__ tb = targ + cell * C_FIELDS;

    // Load both cells fully into registers. Static indexing only -> VGPRs.
    float p[C_FIELDS], t[C_FIELDS];
    #pragma unroll
    for (int k = 0; k < 7; ++k) __builtin_memcpy(&p[k * 4], pb + k * 4, 16);
    __builtin_memcpy(&p[28], pb + 28, 8);
    #pragma unroll
    for (int k = 0; k < 7; ++k) __builtin_memcpy(&t[k * 4], tb + k * 4, 16);
    __builtin_memcpy(&t[28], tb + 28, 8);

    const float tx0 = t[0], ty0 = t[1], tx1 = t[2], ty1 = t[3], t4 = t[4];
    const float a2 = (tx1 - tx0) * (ty1 - ty0);

    // Box A = pred[0:4], Box B = pred[5:9]
    const float ax0 = p[0], ay0 = p[1], ax1 = p[2], ay1 = p[3];
    const float conf = p[4];
    const float bx0 = p[5], by0 = p[6], bx1 = p[7], by1 = p[8];

    const float wA = fmaxf(fminf(ax1, tx1) - fmaxf(ax0, tx0), 0.0f);
    const float hA = fmaxf(fminf(ay1, ty1) - fmaxf(ay0, ty0), 0.0f);
    const float interA = wA * hA;
    const float a1A = (ax1 - ax0) * (ay1 - ay0);
    const float iouA = interA / (a1A + a2 - interA);

    const float wB = fmaxf(fminf(bx1, tx1) - fmaxf(bx0, tx0), 0.0f);
    const float hB = fmaxf(fminf(by1, ty1) - fmaxf(by0, ty0), 0.0f);
    const float interB = wB * hB;
    const float a1B = (bx1 - bx0) * (by1 - by0);
    const float iouB = interB / (a1B + a2 - interB);

    // np.argmax over 2: NaN acts as max, first index wins ties.
    bool pickB;
    if (iouA != iouA)      pickB = false;
    else if (iouB != iouB) pickB = true;
    else                   pickB = (iouB > iouA);

    const float c0 = pickB ? bx0 : ax0;
    const float c1 = pickB ? by0 : ay0;
    const float c2 = pickB ? bx1 : ax1;
    const float c3 = pickB ? by1 : ay1;

    const bool obj = (t4 > 0.0f);

    // loss1: xy
    const float dx = (obj ? c0 : 0.0f) - tx0;
    const float dy = (obj ? c1 : 0.0f) - ty0;
    const float l1 = dx * dx + dy * dy;

    // loss2: sqrt wh
    const float stw = sqrtf(tx1);
    const float sth = sqrtf(ty1);
    float l2;
    if (obj) {
        const float d0 = sqrtf(c2) - stw;
        const float d1 = sqrtf(c3) - sth;
        l2 = d0 * d0 + d1 * d1;
    } else {
        l2 = stw * stw + sth * sth;
    }

    // loss3 / loss4: conf
    const float v3 = (obj ? conf : 0.0f) - t4;
    const float l3 = v3 * v3;
    const float v4 = (obj ? 1.0f : conf) - t4;
    const float l4 = v4 * v4;

    // loss5: cls
    float l5 = 0.0f;
    #pragma unroll
    for (int f = 10; f < 30; ++f) {
        const float v = (obj ? p[f] : 0.0f) - t[f];
        l5 += v * v;
    }

    float acc = LAMBDA_COORD * (l1 + l2) + l3 + LAMBDA_NOOBJ * l4 + l5;

    // Wave-64 butterfly reduce, then cross-wave via tiny LDS, one atomic/block.
    #pragma unroll
    for (int off = 32; off >= 1; off >>= 1)
        acc += __shfl_xor(acc, off, 64);

    const int wave = tid >> 6;
    const int lane = tid & 63;
    if (lane == 0) red[wave] = acc;
    __syncthreads();
    if (tid == 0) {
        const float s = red[0] + red[1] + red[2] + red[3];
        atomicAdd(out, s * inv_b);
    }
}

extern "C" void kernel_launch(void* const* d_in, const int* in_sizes, int n_in,
                              void* d_out, int out_size, void* d_ws, size_t ws_size,
                              hipStream_t stream) {
    const float* pred = (const float*)d_in[0];
    const float* targ = (const float*)d_in[1];
    float* out = (float*)d_out;

    const long long total = (long long)in_sizes[0];     // B*49*30
    const long long cells = total / C_FIELDS;           // 802816
    const long long B = cells / 49;                     // 16384
    const int blocks = (int)(cells / 256);              // 3136 exact
    const float inv_b = 1.0f / (float)B;

    hipMemsetAsync(d_out, 0, sizeof(float), stream);
    yolo_loss_kernel<<<blocks, 256, 0, stream>>>(pred, targ, out, inv_b);
}

// Round 4
// 40.251 us; speedup vs baseline: 1.5645x; 1.4833x over previous
//
#include <hip/hip_runtime.h>

// YOLO loss, fused. R3 theory: the ~70us plateau across 3 structures was the
// 3136 same-address atomicAdds serializing at one cacheline across 8 XCDs.
// R4: two-stage reduction — blocks plain-store partials to d_ws, a tiny
// second kernel reduces 3136 floats and writes out. No atomics, no memset.

#define LAMBDA_COORD 5.0f
#define LAMBDA_NOOBJ 0.5f

constexpr int C_FIELDS = 30;

__global__ __launch_bounds__(256) void yolo_loss_kernel(
    const float* __restrict__ pred, const float* __restrict__ targ,
    float* __restrict__ part)
{
    __shared__ float red[4];

    const int tid = threadIdx.x;
    const long long cell = (long long)blockIdx.x * 256 + tid;
    const float* __restrict__ pb = pred + cell * C_FIELDS;
    const float* __restrict__ tb = targ + cell * C_FIELDS;

    // Per-thread register load of both 120 B cells (7x16B + 1x8B each).
    float p[C_FIELDS], t[C_FIELDS];
    #pragma unroll
    for (int k = 0; k < 7; ++k) __builtin_memcpy(&p[k * 4], pb + k * 4, 16);
    __builtin_memcpy(&p[28], pb + 28, 8);
    #pragma unroll
    for (int k = 0; k < 7; ++k) __builtin_memcpy(&t[k * 4], tb + k * 4, 16);
    __builtin_memcpy(&t[28], tb + 28, 8);

    const float tx0 = t[0], ty0 = t[1], tx1 = t[2], ty1 = t[3], t4 = t[4];
    const float a2 = (tx1 - tx0) * (ty1 - ty0);

    const float ax0 = p[0], ay0 = p[1], ax1 = p[2], ay1 = p[3];
    const float conf = p[4];
    const float bx0 = p[5], by0 = p[6], bx1 = p[7], by1 = p[8];

    const float wA = fmaxf(fminf(ax1, tx1) - fmaxf(ax0, tx0), 0.0f);
    const float hA = fmaxf(fminf(ay1, ty1) - fmaxf(ay0, ty0), 0.0f);
    const float interA = wA * hA;
    const float a1A = (ax1 - ax0) * (ay1 - ay0);
    const float iouA = interA / (a1A + a2 - interA);

    const float wB = fmaxf(fminf(bx1, tx1) - fmaxf(bx0, tx0), 0.0f);
    const float hB = fmaxf(fminf(by1, ty1) - fmaxf(by0, ty0), 0.0f);
    const float interB = wB * hB;
    const float a1B = (bx1 - bx0) * (by1 - by0);
    const float iouB = interB / (a1B + a2 - interB);

    // np.argmax over 2: NaN acts as max, first index wins ties.
    bool pickB;
    if (iouA != iouA)      pickB = false;
    else if (iouB != iouB) pickB = true;
    else                   pickB = (iouB > iouA);

    const float c0 = pickB ? bx0 : ax0;
    const float c1 = pickB ? by0 : ay0;
    const float c2 = pickB ? bx1 : ax1;
    const float c3 = pickB ? by1 : ay1;

    const bool obj = (t4 > 0.0f);

    const float dx = (obj ? c0 : 0.0f) - tx0;
    const float dy = (obj ? c1 : 0.0f) - ty0;
    const float l1 = dx * dx + dy * dy;

    const float stw = sqrtf(tx1);
    const float sth = sqrtf(ty1);
    float l2;
    if (obj) {
        const float d0 = sqrtf(c2) - stw;
        const float d1 = sqrtf(c3) - sth;
        l2 = d0 * d0 + d1 * d1;
    } else {
        l2 = stw * stw + sth * sth;
    }

    const float v3 = (obj ? conf : 0.0f) - t4;
    const float l3 = v3 * v3;
    const float v4 = (obj ? 1.0f : conf) - t4;
    const float l4 = v4 * v4;

    float l5 = 0.0f;
    #pragma unroll
    for (int f = 10; f < 30; ++f) {
        const float v = (obj ? p[f] : 0.0f) - t[f];
        l5 += v * v;
    }

    float acc = LAMBDA_COORD * (l1 + l2) + l3 + LAMBDA_NOOBJ * l4 + l5;

    #pragma unroll
    for (int off = 32; off >= 1; off >>= 1)
        acc += __shfl_xor(acc, off, 64);

    const int wave = tid >> 6;
    const int lane = tid & 63;
    if (lane == 0) red[wave] = acc;
    __syncthreads();
    if (tid == 0)
        part[blockIdx.x] = red[0] + red[1] + red[2] + red[3];  // plain store, no atomic
}

__global__ __launch_bounds__(256) void yolo_reduce_kernel(
    const float* __restrict__ part, float* __restrict__ out,
    int n, float inv_b)
{
    __shared__ float red[4];
    const int tid = threadIdx.x;
    float acc = 0.0f;
    for (int i = tid; i < n; i += 256) acc += part[i];
    #pragma unroll
    for (int off = 32; off >= 1; off >>= 1)
        acc += __shfl_xor(acc, off, 64);
    const int wave = tid >> 6;
    const int lane = tid & 63;
    if (lane == 0) red[wave] = acc;
    __syncthreads();
    if (tid == 0)
        out[0] = (red[0] + red[1] + red[2] + red[3]) * inv_b;
}

extern "C" void kernel_launch(void* const* d_in, const int* in_sizes, int n_in,
                              void* d_out, int out_size, void* d_ws, size_t ws_size,
                              hipStream_t stream) {
    const float* pred = (const float*)d_in[0];
    const float* targ = (const float*)d_in[1];
    float* out = (float*)d_out;
    float* part = (float*)d_ws;                         // 3136 floats = 12.5 KB

    const long long total = (long long)in_sizes[0];     // B*49*30
    const long long cells = total / C_FIELDS;           // 802816
    const long long B = cells / 49;                     // 16384
    const int blocks = (int)(cells / 256);              // 3136 exact
    const float inv_b = 1.0f / (float)B;

    yolo_loss_kernel<<<blocks, 256, 0, stream>>>(pred, targ, part);
    yolo_reduce_kernel<<<1, 256, 0, stream>>>(part, out, blocks, inv_b);
}

// Round 5
// 36.718 us; speedup vs baseline: 1.7150x; 1.0962x over previous
//
#include <hip/hip_runtime.h>

// YOLO loss, fused, two-stage reduction (no atomics — R4 removed the 3136
// same-address atomicAdd serialization, -20us).
// R5: force full memory-level parallelism. R4's kernel compiled to VGPR=32,
// i.e. the compiler serialized the 16 per-thread loads into dependent groups
// (only ~4-6 in flight). A sched_barrier(0) between the load block and the
// compute block forces all 16 loads to issue back-to-back (results all live:
// ~60 VGPRs), hiding ~900cy HBM latency with ILP x TLP.

#define LAMBDA_COORD 5.0f
#define LAMBDA_NOOBJ 0.5f

constexpr int C_FIELDS = 30;

__global__ __launch_bounds__(256) void yolo_loss_kernel(
    const float* __restrict__ pred, const float* __restrict__ targ,
    float* __restrict__ part)
{
    __shared__ float red[4];

    const int tid = threadIdx.x;
    const long long cell = (long long)blockIdx.x * 256 + tid;
    const float* __restrict__ pb = pred + cell * C_FIELDS;
    const float* __restrict__ tb = targ + cell * C_FIELDS;

    // Issue ALL loads (2 x 120 B per thread) before any use.
    float p[C_FIELDS], t[C_FIELDS];
    #pragma unroll
    for (int k = 0; k < 7; ++k) __builtin_memcpy(&p[k * 4], pb + k * 4, 16);
    __builtin_memcpy(&p[28], pb + 28, 8);
    #pragma unroll
    for (int k = 0; k < 7; ++k) __builtin_memcpy(&t[k * 4], tb + k * 4, 16);
    __builtin_memcpy(&t[28], tb + 28, 8);

    // Hard scheduling fence: nothing moves across. All 16 loads stay issued
    // above; compute (and its s_waitcnt) stays below.
    __builtin_amdgcn_sched_barrier(0);

    const float tx0 = t[0], ty0 = t[1], tx1 = t[2], ty1 = t[3], t4 = t[4];
    const float a2 = (tx1 - tx0) * (ty1 - ty0);

    const float ax0 = p[0], ay0 = p[1], ax1 = p[2], ay1 = p[3];
    const float conf = p[4];
    const float bx0 = p[5], by0 = p[6], bx1 = p[7], by1 = p[8];

    const float wA = fmaxf(fminf(ax1, tx1) - fmaxf(ax0, tx0), 0.0f);
    const float hA = fmaxf(fminf(ay1, ty1) - fmaxf(ay0, ty0), 0.0f);
    const float interA = wA * hA;
    const float a1A = (ax1 - ax0) * (ay1 - ay0);
    const float iouA = interA / (a1A + a2 - interA);

    const float wB = fmaxf(fminf(bx1, tx1) - fmaxf(bx0, tx0), 0.0f);
    const float hB = fmaxf(fminf(by1, ty1) - fmaxf(by0, ty0), 0.0f);
    const float interB = wB * hB;
    const float a1B = (bx1 - bx0) * (by1 - by0);
    const float iouB = interB / (a1B + a2 - interB);

    // np.argmax over 2: NaN acts as max, first index wins ties.
    bool pickB;
    if (iouA != iouA)      pickB = false;
    else if (iouB != iouB) pickB = true;
    else                   pickB = (iouB > iouA);

    const float c0 = pickB ? bx0 : ax0;
    const float c1 = pickB ? by0 : ay0;
    const float c2 = pickB ? bx1 : ax1;
    const float c3 = pickB ? by1 : ay1;

    const bool obj = (t4 > 0.0f);

    const float dx = (obj ? c0 : 0.0f) - tx0;
    const float dy = (obj ? c1 : 0.0f) - ty0;
    const float l1 = dx * dx + dy * dy;

    const float stw = sqrtf(tx1);
    const float sth = sqrtf(ty1);
    float l2;
    if (obj) {
        const float d0 = sqrtf(c2) - stw;
        const float d1 = sqrtf(c3) - sth;
        l2 = d0 * d0 + d1 * d1;
    } else {
        l2 = stw * stw + sth * sth;
    }

    const float v3 = (obj ? conf : 0.0f) - t4;
    const float l3 = v3 * v3;
    const float v4 = (obj ? 1.0f : conf) - t4;
    const float l4 = v4 * v4;

    float l5 = 0.0f;
    #pragma unroll
    for (int f = 10; f < 30; ++f) {
        const float v = (obj ? p[f] : 0.0f) - t[f];
        l5 += v * v;
    }

    float acc = LAMBDA_COORD * (l1 + l2) + l3 + LAMBDA_NOOBJ * l4 + l5;

    #pragma unroll
    for (int off = 32; off >= 1; off >>= 1)
        acc += __shfl_xor(acc, off, 64);

    const int wave = tid >> 6;
    const int lane = tid & 63;
    if (lane == 0) red[wave] = acc;
    __syncthreads();
    if (tid == 0)
        part[blockIdx.x] = red[0] + red[1] + red[2] + red[3];  // plain store
}

__global__ __launch_bounds__(256) void yolo_reduce_kernel(
    const float* __restrict__ part, float* __restrict__ out,
    int n, float inv_b)
{
    __shared__ float red[4];
    const int tid = threadIdx.x;
    float acc = 0.0f;
    for (int i = tid; i < n; i += 256) acc += part[i];
    #pragma unroll
    for (int off = 32; off >= 1; off >>= 1)
        acc += __shfl_xor(acc, off, 64);
    const int wave = tid >> 6;
    const int lane = tid & 63;
    if (lane == 0) red[wave] = acc;
    __syncthreads();
    if (tid == 0)
        out[0] = (red[0] + red[1] + red[2] + red[3]) * inv_b;
}

extern "C" void kernel_launch(void* const* d_in, const int* in_sizes, int n_in,
                              void* d_out, int out_size, void* d_ws, size_t ws_size,
                              hipStream_t stream) {
    const float* pred = (const float*)d_in[0];
    const float* targ = (const float*)d_in[1];
    float* out = (float*)d_out;
    float* part = (float*)d_ws;                         // 3136 floats

    const long long total = (long long)in_sizes[0];     // B*49*30
    const long long cells = total / C_FIELDS;           // 802816
    const long long B = cells / 49;                     // 16384
    const int blocks = (int)(cells / 256);              // 3136 exact
    const float inv_b = 1.0f / (float)B;

    yolo_loss_kernel<<<blocks, 256, 0, stream>>>(pred, targ, part);
    yolo_reduce_kernel<<<1, 256, 0, stream>>>(part, out, blocks, inv_b);
}

// Round 6
// 34.630 us; speedup vs baseline: 1.8184x; 1.0603x over previous
//
#include <hip/hip_runtime.h>

// YOLO loss, fused, two-stage reduction (no atomics).
// R6: force real MLP. Cell base = cell*120 B is 8B-aligned (not 16B), so use
// 15 float2 loads per array into fully-unrolled register arrays. All
// consumers sit below sched_barrier(0): ~28 dwordx2 loads in flight per
// thread (t[6..9]/p[9] DCE), ~56 live result VGPRs. VGPR_Count in the next
// profile is the direct test: ~80 => MLP achieved.

#define LAMBDA_COORD 5.0f
#define LAMBDA_NOOBJ 0.5f

constexpr int C_FIELDS = 30;

__global__ __launch_bounds__(256) void yolo_loss_kernel(
    const float* __restrict__ pred, const float* __restrict__ targ,
    float* __restrict__ part)
{
    __shared__ float red[4];

    const int tid = threadIdx.x;
    const long long cell = (long long)blockIdx.x * 256 + tid;
    const float2* __restrict__ pv = (const float2*)(pred + cell * C_FIELDS); // 8B aligned
    const float2* __restrict__ tv = (const float2*)(targ + cell * C_FIELDS); // 8B aligned

    // Issue every load before any use. Static indices -> registers.
    float2 P[15], T[15];
    #pragma unroll
    for (int k = 0; k < 15; ++k) P[k] = pv[k];
    #pragma unroll
    for (int k = 0; k < 15; ++k) T[k] = tv[k];

    // Nothing crosses: loads (and no waits) above, compute + waits below.
    __builtin_amdgcn_sched_barrier(0);

    const float tx0 = T[0].x, ty0 = T[0].y, tx1 = T[1].x, ty1 = T[1].y;
    const float t4  = T[2].x;
    const float a2 = (tx1 - tx0) * (ty1 - ty0);

    const float ax0 = P[0].x, ay0 = P[0].y, ax1 = P[1].x, ay1 = P[1].y;
    const float conf = P[2].x;
    const float bx0 = P[2].y, by0 = P[3].x, bx1 = P[3].y, by1 = P[4].x;

    const float wA = fmaxf(fminf(ax1, tx1) - fmaxf(ax0, tx0), 0.0f);
    const float hA = fmaxf(fminf(ay1, ty1) - fmaxf(ay0, ty0), 0.0f);
    const float interA = wA * hA;
    const float a1A = (ax1 - ax0) * (ay1 - ay0);
    const float iouA = interA / (a1A + a2 - interA);

    const float wB = fmaxf(fminf(bx1, tx1) - fmaxf(bx0, tx0), 0.0f);
    const float hB = fmaxf(fminf(by1, ty1) - fmaxf(by0, ty0), 0.0f);
    const float interB = wB * hB;
    const float a1B = (bx1 - bx0) * (by1 - by0);
    const float iouB = interB / (a1B + a2 - interB);

    // np.argmax over 2: NaN acts as max, first index wins ties.
    bool pickB;
    if (iouA != iouA)      pickB = false;
    else if (iouB != iouB) pickB = true;
    else                   pickB = (iouB > iouA);

    const float c0 = pickB ? bx0 : ax0;
    const float c1 = pickB ? by0 : ay0;
    const float c2 = pickB ? bx1 : ax1;
    const float c3 = pickB ? by1 : ay1;

    const bool obj = (t4 > 0.0f);

    // loss1: xy
    const float dx = (obj ? c0 : 0.0f) - tx0;
    const float dy = (obj ? c1 : 0.0f) - ty0;
    const float l1 = dx * dx + dy * dy;

    // loss2: sqrt wh
    const float stw = sqrtf(tx1);
    const float sth = sqrtf(ty1);
    float l2;
    if (obj) {
        const float d0 = sqrtf(c2) - stw;
        const float d1 = sqrtf(c3) - sth;
        l2 = d0 * d0 + d1 * d1;
    } else {
        l2 = stw * stw + sth * sth;
    }

    // loss3 / loss4: conf
    const float v3 = (obj ? conf : 0.0f) - t4;
    const float l3 = v3 * v3;
    const float v4 = (obj ? 1.0f : conf) - t4;
    const float l4 = v4 * v4;

    // loss5: cls fields 10..29 = float2 slots 5..14
    float l5 = 0.0f;
    #pragma unroll
    for (int k = 5; k < 15; ++k) {
        const float va = (obj ? P[k].x : 0.0f) - T[k].x;
        const float vb = (obj ? P[k].y : 0.0f) - T[k].y;
        l5 += va * va + vb * vb;
    }

    float acc = LAMBDA_COORD * (l1 + l2) + l3 + LAMBDA_NOOBJ * l4 + l5;

    #pragma unroll
    for (int off = 32; off >= 1; off >>= 1)
        acc += __shfl_xor(acc, off, 64);

    const int wave = tid >> 6;
    const int lane = tid & 63;
    if (lane == 0) red[wave] = acc;
    __syncthreads();
    if (tid == 0)
        part[blockIdx.x] = red[0] + red[1] + red[2] + red[3];  // plain store
}

__global__ __launch_bounds__(256) void yolo_reduce_kernel(
    const float* __restrict__ part, float* __restrict__ out,
    int n, float inv_b)
{
    __shared__ float red[4];
    const int tid = threadIdx.x;
    float acc = 0.0f;
    const float4* p4 = (const float4*)part;
    for (int i = tid; i < n / 4; i += 256) {
        const float4 v = p4[i];
        acc += v.x + v.y + v.z + v.w;
    }
    #pragma unroll
    for (int off = 32; off >= 1; off >>= 1)
        acc += __shfl_xor(acc, off, 64);
    const int wave = tid >> 6;
    const int lane = tid & 63;
    if (lane == 0) red[wave] = acc;
    __syncthreads();
    if (tid == 0)
        out[0] = (red[0] + red[1] + red[2] + red[3]) * inv_b;
}

extern "C" void kernel_launch(void* const* d_in, const int* in_sizes, int n_in,
                              void* d_out, int out_size, void* d_ws, size_t ws_size,
                              hipStream_t stream) {
    const float* pred = (const float*)d_in[0];
    const float* targ = (const float*)d_in[1];
    float* out = (float*)d_out;
    float* part = (float*)d_ws;                         // 3136 floats

    const long long total = (long long)in_sizes[0];     // B*49*30
    const long long cells = total / C_FIELDS;           // 802816
    const long long B = cells / 49;                     // 16384
    const int blocks = (int)(cells / 256);              // 3136 exact, %4==0
    const float inv_b = 1.0f / (float)B;

    yolo_loss_kernel<<<blocks, 256, 0, stream>>>(pred, targ, part);
    yolo_reduce_kernel<<<1, 256, 0, stream>>>(part, out, blocks, inv_b);
}